// Round 10
// baseline (200.326 us; speedup 1.0000x reference)
//
#include <hip/hip_runtime.h>

// QKBmm: out[b,m,q,kv] = sum_h q[b,m,q,h] * k[b,m,kv,h]
// B=2, M=16, QT=1024, KVT=4096, H=128. fp32 in/out, bf16 MFMA compute.
// Write-bound: 512 MB out; inputs L3-resident. Floor ~91us @6.7TB/s.
// R6 WIN 122.6 (4 blk/CU). R7 FAILED (spill). R8 121.9 (5 blk/CU, neutral).
// R9 FAILED (149): manual counted-vmcnt pipeline — barrier overhead + LDS
//     write conflicts; HW cross-block overlap beats source pipelining here.
// R10: single-variable A/B vs R8 — plain cached stores instead of NT.
//     Theory: L2 write-back accumulates dirty lines and evicts in DRAM-
//     friendly batches (the 6.7TB/s fill kernel uses plain stores); NT
//     streams scattered 64B segments. FETCH_SIZE arbitrates: if it stays
//     low and dur drops, NT was the residual cost; if FETCH balloons, NT
//     was protective and we keep it.

#define QT   1024
#define KVT  4096
#define HD   128
#define NXCD 8

using bf16x8 = __attribute__((ext_vector_type(8))) __bf16;
using bf16x4 = __attribute__((ext_vector_type(4))) __bf16;
using f32x4  = __attribute__((ext_vector_type(4))) float;

__global__ __launch_bounds__(256, 5)
void QKBmm_74062416052397_kernel(const float* __restrict__ q,
                                 const float* __restrict__ k,
                                 float* __restrict__ out) {
    // Half-K (64-col) buffers: A 64x64 (8KB), B 128x64 (16KB) = 24KB total.
    __shared__ __bf16 As[64 * 64];
    __shared__ __bf16 Bs[128 * 64];

    const int t = threadIdx.x;         // 0..255

    // XCD-aware remap (bijective, 16384%8==0): n fastest, then m, then bm.
    const unsigned lin = blockIdx.x;
    const unsigned swz = (lin & (NXCD - 1)) * (16384u / NXCD) + (lin >> 3);
    const int nt_ = swz & 31;          // KV tile index (128 cols, fastest)
    const int mt  = (swz >> 5) & 15;   // Q tile index (64 rows)
    const int bm  = swz >> 9;          // batch*M index
    const int m0  = mt * 64;
    const int n0  = nt_ * 128;

    const float4* __restrict__ Q4 =
        reinterpret_cast<const float4*>(q + ((size_t)bm * QT  + m0) * HD);
    const float4* __restrict__ K4 =
        reinterpret_cast<const float4*>(k + ((size_t)bm * KVT + n0) * HD);

    const int lane = t & 63;
    const int wid  = t >> 6;
    const int wm   = (wid >> 1) * 32;  // wave row offset within 64-row tile
    const int wn   = (wid & 1) * 64;   // wave col offset within 128-col tile
    const int lr   = lane & 15;        // fragment row index
    const int lg   = lane >> 4;        // k-group 0..3

    f32x4 acc[2][4] = {};              // [mi][ni] -> 32 VGPR

    // Staging per half h (fp32 cols h*64.., f4 cols h*16..):
    //   A: 64 rows x 16 f4 = 1024 f4 -> 4 per thread
    //   B: 128 rows x 16 f4 = 2048 f4 -> 8 per thread
    // f = it*256 + t; row = f>>4; c4 = f&15.
    // LDS elem e = (row*64 + c4*4) ^ ((row&7)<<3)  (XOR swizzle).
#pragma unroll
    for (int h = 0; h < 2; ++h) {
        if (h) __syncthreads();        // prior compute done reading the buffer

        // batch 1: A it0-1 + B it0-1 (16 VGPR transient)
        {
            float4 v0, v1, v2, v3;
            int f0 = t,          r0 = f0 >> 4, c0 = f0 & 15;
            int f1 = 256 + t,    r1 = f1 >> 4, c1 = f1 & 15;
            v0 = Q4[r0 * 32 + h * 16 + c0];
            v1 = Q4[r1 * 32 + h * 16 + c1];
            v2 = K4[r0 * 32 + h * 16 + c0];
            v3 = K4[r1 * 32 + h * 16 + c1];
            int e0 = (r0 * 64 + c0 * 4) ^ ((r0 & 7) << 3);
            int e1 = (r1 * 64 + c1 * 4) ^ ((r1 & 7) << 3);
            *reinterpret_cast<bf16x4*>(&As[e0]) =
                bf16x4{ (__bf16)v0.x, (__bf16)v0.y, (__bf16)v0.z, (__bf16)v0.w };
            *reinterpret_cast<bf16x4*>(&As[e1]) =
                bf16x4{ (__bf16)v1.x, (__bf16)v1.y, (__bf16)v1.z, (__bf16)v1.w };
            *reinterpret_cast<bf16x4*>(&Bs[e0]) =
                bf16x4{ (__bf16)v2.x, (__bf16)v2.y, (__bf16)v2.z, (__bf16)v2.w };
            *reinterpret_cast<bf16x4*>(&Bs[e1]) =
                bf16x4{ (__bf16)v3.x, (__bf16)v3.y, (__bf16)v3.z, (__bf16)v3.w };
        }
        // batch 2: A it2-3 + B it2-3
        {
            float4 v0, v1, v2, v3;
            int f0 = 512 + t,    r0 = f0 >> 4, c0 = f0 & 15;
            int f1 = 768 + t,    r1 = f1 >> 4, c1 = f1 & 15;
            v0 = Q4[r0 * 32 + h * 16 + c0];
            v1 = Q4[r1 * 32 + h * 16 + c1];
            v2 = K4[r0 * 32 + h * 16 + c0];
            v3 = K4[r1 * 32 + h * 16 + c1];
            int e0 = (r0 * 64 + c0 * 4) ^ ((r0 & 7) << 3);
            int e1 = (r1 * 64 + c1 * 4) ^ ((r1 & 7) << 3);
            *reinterpret_cast<bf16x4*>(&As[e0]) =
                bf16x4{ (__bf16)v0.x, (__bf16)v0.y, (__bf16)v0.z, (__bf16)v0.w };
            *reinterpret_cast<bf16x4*>(&As[e1]) =
                bf16x4{ (__bf16)v1.x, (__bf16)v1.y, (__bf16)v1.z, (__bf16)v1.w };
            *reinterpret_cast<bf16x4*>(&Bs[e0]) =
                bf16x4{ (__bf16)v2.x, (__bf16)v2.y, (__bf16)v2.z, (__bf16)v2.w };
            *reinterpret_cast<bf16x4*>(&Bs[e1]) =
                bf16x4{ (__bf16)v3.x, (__bf16)v3.y, (__bf16)v3.z, (__bf16)v3.w };
        }
        // batch 3: B it4-7
        {
            float4 v0, v1, v2, v3;
            int f0 = 1024 + t, r0 = f0 >> 4, c0 = f0 & 15;
            int f1 = 1280 + t, r1 = f1 >> 4, c1 = f1 & 15;
            int f2 = 1536 + t, r2 = f2 >> 4, c2 = f2 & 15;
            int f3 = 1792 + t, r3 = f3 >> 4, c3 = f3 & 15;
            v0 = K4[r0 * 32 + h * 16 + c0];
            v1 = K4[r1 * 32 + h * 16 + c1];
            v2 = K4[r2 * 32 + h * 16 + c2];
            v3 = K4[r3 * 32 + h * 16 + c3];
            int e0 = (r0 * 64 + c0 * 4) ^ ((r0 & 7) << 3);
            int e1 = (r1 * 64 + c1 * 4) ^ ((r1 & 7) << 3);
            int e2 = (r2 * 64 + c2 * 4) ^ ((r2 & 7) << 3);
            int e3 = (r3 * 64 + c3 * 4) ^ ((r3 & 7) << 3);
            *reinterpret_cast<bf16x4*>(&Bs[e0]) =
                bf16x4{ (__bf16)v0.x, (__bf16)v0.y, (__bf16)v0.z, (__bf16)v0.w };
            *reinterpret_cast<bf16x4*>(&Bs[e1]) =
                bf16x4{ (__bf16)v1.x, (__bf16)v1.y, (__bf16)v1.z, (__bf16)v1.w };
            *reinterpret_cast<bf16x4*>(&Bs[e2]) =
                bf16x4{ (__bf16)v2.x, (__bf16)v2.y, (__bf16)v2.z, (__bf16)v2.w };
            *reinterpret_cast<bf16x4*>(&Bs[e3]) =
                bf16x4{ (__bf16)v3.x, (__bf16)v3.y, (__bf16)v3.z, (__bf16)v3.w };
        }
        __syncthreads();

        // ---- Compute 2 K-steps from the staged half.
        //      bfr[4] live; af loaded per-mi (live frags = 20 VGPR). ----
#pragma unroll
        for (int ks = 0; ks < 2; ++ks) {
            const int kcol = ks * 32 + lg * 8;
            bf16x8 bfr[4];
#pragma unroll
            for (int ni = 0; ni < 4; ++ni) {
                int r = wn + ni * 16 + lr;
                int e = (r * 64 + kcol) ^ ((r & 7) << 3);
                bfr[ni] = *reinterpret_cast<const bf16x8*>(&Bs[e]);
            }
#pragma unroll
            for (int mi = 0; mi < 2; ++mi) {
                int r = wm + mi * 16 + lr;
                int e = (r * 64 + kcol) ^ ((r & 7) << 3);
                bf16x8 af = *reinterpret_cast<const bf16x8*>(&As[e]);
#pragma unroll
                for (int ni = 0; ni < 4; ++ni)
                    acc[mi][ni] = __builtin_amdgcn_mfma_f32_16x16x32_bf16(
                        af, bfr[ni], acc[mi][ni], 0, 0, 0);
            }
        }
    }

    // ---- Epilogue: R2/R6 proven geometry, but PLAIN cached stores (A/B
    //      vs R8's NT). One instr = 4 rows x 64B segments; adjacent
    //      ni-instrs complete 128B lines; L2 write-back batches eviction.
    float* __restrict__ Cp = out + (size_t)bm * QT * KVT;
#pragma unroll
    for (int mi = 0; mi < 2; ++mi) {
#pragma unroll
        for (int j = 0; j < 4; ++j) {
            int row = m0 + wm + mi * 16 + lg * 4 + j;
            float* rp = Cp + (size_t)row * KVT + n0 + wn;
#pragma unroll
            for (int ni = 0; ni < 4; ++ni)
                rp[ni * 16 + lr] = acc[mi][ni][j];
        }
    }
}

extern "C" void kernel_launch(void* const* d_in, const int* in_sizes, int n_in,
                              void* d_out, int out_size, void* d_ws, size_t ws_size,
                              hipStream_t stream) {
    const float* q = (const float*)d_in[0];
    const float* k = (const float*)d_in[1];
    float* out = (float*)d_out;

    QKBmm_74062416052397_kernel<<<dim3(16384), dim3(256), 0, stream>>>(q, k, out);
}

// Round 11
// 118.689 us; speedup vs baseline: 1.6878x; 1.6878x over previous
//
#include <hip/hip_runtime.h>

// QKBmm: out[b,m,q,kv] = sum_h q[b,m,q,h] * k[b,m,kv,h]
// B=2, M=16, QT=1024, KVT=4096, H=128. fp32 in/out, bf16 MFMA compute.
// Write-bound: 512 MB out; inputs L3-resident. Floor ~91us @6.7TB/s.
// R6 WIN 122.6 (4 blk/CU). R8 121.9 (5 blk/CU). R9 FAILED (manual pipeline).
// R10 FAILED (200us): plain cached stores — NT is essential (L2 protection).
// R11: 32x32x16 MFMA so C/D col=lane&31 -> every scalar NT store instruction
//     writes 2 FULL 128B lines (vs R8's 4x64B half-lines needing NT merge).
//     Everything else = R8 (tile, staging, swizzle, occupancy).

#define QT   1024
#define KVT  4096
#define HD   128
#define NXCD 8

using bf16x8 = __attribute__((ext_vector_type(8))) __bf16;
using bf16x4 = __attribute__((ext_vector_type(4))) __bf16;
using f32x16 = __attribute__((ext_vector_type(16))) float;

__global__ __launch_bounds__(256, 5)
void QKBmm_74062416052397_kernel(const float* __restrict__ q,
                                 const float* __restrict__ k,
                                 float* __restrict__ out) {
    // Half-K (64-col) buffers: A 64x64 (8KB), B 128x64 (16KB) = 24KB total.
    __shared__ __bf16 As[64 * 64];
    __shared__ __bf16 Bs[128 * 64];

    const int t = threadIdx.x;         // 0..255

    // XCD-aware remap (bijective, 16384%8==0): n fastest, then m, then bm.
    const unsigned lin = blockIdx.x;
    const unsigned swz = (lin & (NXCD - 1)) * (16384u / NXCD) + (lin >> 3);
    const int nt_ = swz & 31;          // KV tile index (128 cols, fastest)
    const int mt  = (swz >> 5) & 15;   // Q tile index (64 rows)
    const int bm  = swz >> 9;          // batch*M index
    const int m0  = mt * 64;
    const int n0  = nt_ * 128;

    const float4* __restrict__ Q4 =
        reinterpret_cast<const float4*>(q + ((size_t)bm * QT  + m0) * HD);
    const float4* __restrict__ K4 =
        reinterpret_cast<const float4*>(k + ((size_t)bm * KVT + n0) * HD);

    const int lane = t & 63;
    const int wid  = t >> 6;
    const int wm   = (wid >> 1) * 32;  // wave row offset (2x2 waves, 32x64 each)
    const int wn   = (wid & 1) * 64;   // wave col offset
    const int l31  = lane & 31;        // fragment row/col index (32-wide)
    const int kh   = (lane >> 5) * 8;  // k-half offset within K=16 step

    f32x16 acc[2] = {};                // [ni] -> 32 VGPR

    // Staging per half h (fp32 cols h*64.., f4 cols h*16..):
    //   A: 64 rows x 16 f4 = 1024 f4 -> 4 per thread
    //   B: 128 rows x 16 f4 = 2048 f4 -> 8 per thread
    // f = it*256 + t; row = f>>4; c4 = f&15.
    // LDS elem e = (row*64 + c4*4) ^ ((row&7)<<3)  (XOR swizzle, 16B units).
#pragma unroll
    for (int h = 0; h < 2; ++h) {
        if (h) __syncthreads();        // prior compute done reading the buffer

        // batch 1: A it0-1 + B it0-1 (16 VGPR transient)
        {
            float4 v0, v1, v2, v3;
            int f0 = t,          r0 = f0 >> 4, c0 = f0 & 15;
            int f1 = 256 + t,    r1 = f1 >> 4, c1 = f1 & 15;
            v0 = Q4[r0 * 32 + h * 16 + c0];
            v1 = Q4[r1 * 32 + h * 16 + c1];
            v2 = K4[r0 * 32 + h * 16 + c0];
            v3 = K4[r1 * 32 + h * 16 + c1];
            int e0 = (r0 * 64 + c0 * 4) ^ ((r0 & 7) << 3);
            int e1 = (r1 * 64 + c1 * 4) ^ ((r1 & 7) << 3);
            *reinterpret_cast<bf16x4*>(&As[e0]) =
                bf16x4{ (__bf16)v0.x, (__bf16)v0.y, (__bf16)v0.z, (__bf16)v0.w };
            *reinterpret_cast<bf16x4*>(&As[e1]) =
                bf16x4{ (__bf16)v1.x, (__bf16)v1.y, (__bf16)v1.z, (__bf16)v1.w };
            *reinterpret_cast<bf16x4*>(&Bs[e0]) =
                bf16x4{ (__bf16)v2.x, (__bf16)v2.y, (__bf16)v2.z, (__bf16)v2.w };
            *reinterpret_cast<bf16x4*>(&Bs[e1]) =
                bf16x4{ (__bf16)v3.x, (__bf16)v3.y, (__bf16)v3.z, (__bf16)v3.w };
        }
        // batch 2: A it2-3 + B it2-3
        {
            float4 v0, v1, v2, v3;
            int f0 = 512 + t,    r0 = f0 >> 4, c0 = f0 & 15;
            int f1 = 768 + t,    r1 = f1 >> 4, c1 = f1 & 15;
            v0 = Q4[r0 * 32 + h * 16 + c0];
            v1 = Q4[r1 * 32 + h * 16 + c1];
            v2 = K4[r0 * 32 + h * 16 + c0];
            v3 = K4[r1 * 32 + h * 16 + c1];
            int e0 = (r0 * 64 + c0 * 4) ^ ((r0 & 7) << 3);
            int e1 = (r1 * 64 + c1 * 4) ^ ((r1 & 7) << 3);
            *reinterpret_cast<bf16x4*>(&As[e0]) =
                bf16x4{ (__bf16)v0.x, (__bf16)v0.y, (__bf16)v0.z, (__bf16)v0.w };
            *reinterpret_cast<bf16x4*>(&As[e1]) =
                bf16x4{ (__bf16)v1.x, (__bf16)v1.y, (__bf16)v1.z, (__bf16)v1.w };
            *reinterpret_cast<bf16x4*>(&Bs[e0]) =
                bf16x4{ (__bf16)v2.x, (__bf16)v2.y, (__bf16)v2.z, (__bf16)v2.w };
            *reinterpret_cast<bf16x4*>(&Bs[e1]) =
                bf16x4{ (__bf16)v3.x, (__bf16)v3.y, (__bf16)v3.z, (__bf16)v3.w };
        }
        // batch 3: B it4-7
        {
            float4 v0, v1, v2, v3;
            int f0 = 1024 + t, r0 = f0 >> 4, c0 = f0 & 15;
            int f1 = 1280 + t, r1 = f1 >> 4, c1 = f1 & 15;
            int f2 = 1536 + t, r2 = f2 >> 4, c2 = f2 & 15;
            int f3 = 1792 + t, r3 = f3 >> 4, c3 = f3 & 15;
            v0 = K4[r0 * 32 + h * 16 + c0];
            v1 = K4[r1 * 32 + h * 16 + c1];
            v2 = K4[r2 * 32 + h * 16 + c2];
            v3 = K4[r3 * 32 + h * 16 + c3];
            int e0 = (r0 * 64 + c0 * 4) ^ ((r0 & 7) << 3);
            int e1 = (r1 * 64 + c1 * 4) ^ ((r1 & 7) << 3);
            int e2 = (r2 * 64 + c2 * 4) ^ ((r2 & 7) << 3);
            int e3 = (r3 * 64 + c3 * 4) ^ ((r3 & 7) << 3);
            *reinterpret_cast<bf16x4*>(&Bs[e0]) =
                bf16x4{ (__bf16)v0.x, (__bf16)v0.y, (__bf16)v0.z, (__bf16)v0.w };
            *reinterpret_cast<bf16x4*>(&Bs[e1]) =
                bf16x4{ (__bf16)v1.x, (__bf16)v1.y, (__bf16)v1.z, (__bf16)v1.w };
            *reinterpret_cast<bf16x4*>(&Bs[e2]) =
                bf16x4{ (__bf16)v2.x, (__bf16)v2.y, (__bf16)v2.z, (__bf16)v2.w };
            *reinterpret_cast<bf16x4*>(&Bs[e3]) =
                bf16x4{ (__bf16)v3.x, (__bf16)v3.y, (__bf16)v3.z, (__bf16)v3.w };
        }
        __syncthreads();

        // ---- Compute 4 K-steps (K=16 each) from the staged half.
        //      32x32x16: A row = lane&31, k = (lane>>5)*8 + j; B symmetric.
#pragma unroll
        for (int ks = 0; ks < 4; ++ks) {
            const int kcol = ks * 16 + kh;
            int ra = wm + l31;
            int ea = (ra * 64 + kcol) ^ ((ra & 7) << 3);
            bf16x8 af = *reinterpret_cast<const bf16x8*>(&As[ea]);
#pragma unroll
            for (int ni = 0; ni < 2; ++ni) {
                int rb = wn + ni * 32 + l31;
                int eb = (rb * 64 + kcol) ^ ((rb & 7) << 3);
                bf16x8 bfr = *reinterpret_cast<const bf16x8*>(&Bs[eb]);
                acc[ni] = __builtin_amdgcn_mfma_f32_32x32x16_bf16(
                    af, bfr, acc[ni], 0, 0, 0);
            }
        }
    }

    // ---- Epilogue: 32x32 C/D layout: col = lane&31 (contiguous 128B),
    //      row = (r&3) + 8*(r>>2) + 4*(lane>>5). Each scalar NT dword store
    //      instruction writes 2 complete 128B lines — zero partial lines.
    float* __restrict__ Cp = out + (size_t)bm * QT * KVT;
#pragma unroll
    for (int ni = 0; ni < 2; ++ni) {
#pragma unroll
        for (int r = 0; r < 16; ++r) {
            int row = m0 + wm + (r & 3) + 8 * (r >> 2) + 4 * (lane >> 5);
            float* rp = Cp + (size_t)row * KVT + n0 + wn + ni * 32 + l31;
            __builtin_nontemporal_store(acc[ni][r], rp);
        }
    }
}

extern "C" void kernel_launch(void* const* d_in, const int* in_sizes, int n_in,
                              void* d_out, int out_size, void* d_ws, size_t ws_size,
                              hipStream_t stream) {
    const float* q = (const float*)d_in[0];
    const float* k = (const float*)d_in[1];
    float* out = (float*)d_out;

    QKBmm_74062416052397_kernel<<<dim3(16384), dim3(256), 0, stream>>>(q, k, out);
}